// Round 1
// baseline (685.001 us; speedup 1.0000x reference)
//
#include <hip/hip_runtime.h>
#include <hip/hip_bf16.h>

#define NN   13824     // 24^3 neurons
#define BB   256       // batch
#define KDIM 512       // input dim
#define ODIM 1000      // output dim
#define CUBE 24
#define KS   16        // out-gemm split-K

typedef short bf8 __attribute__((ext_vector_type(8)));     // 8 bf16 (4 VGPRs)
typedef float f32x4 __attribute__((ext_vector_type(4)));   // MFMA acc

__device__ __forceinline__ float fast_tanh(float a) {
    float e = __expf(2.0f * a);
    return 1.0f - 2.0f / (e + 1.0f);
}
__device__ __forceinline__ float bf_lo(unsigned u) { return __uint_as_float(u << 16); }
__device__ __forceinline__ float bf_hi(unsigned u) { return __uint_as_float(u & 0xffff0000u); }
__device__ __forceinline__ unsigned short bf_rne(float f) {
    unsigned u = __float_as_uint(f);
    u += 0x7fffu + ((u >> 16) & 1u);
    return (unsigned short)(u >> 16);
}
// packed fp32x2 -> bf16x2 via v_cvt_pk_bf16_f32 (one inst on gfx950)
__device__ __forceinline__ unsigned pk_bf16(float lo, float hi) {
    union { __hip_bfloat162 h; unsigned u; } cv;
    cv.h = __float22bfloat162_rn(make_float2(lo, hi));
    return cv.u;
}
__device__ __forceinline__ bf8 cvt8(float4 a, float4 b) {
    union { bf8 v; unsigned u[4]; } r;
    r.u[0] = pk_bf16(a.x, a.y);
    r.u[1] = pk_bf16(a.z, a.w);
    r.u[2] = pk_bf16(b.x, b.y);
    r.u[3] = pk_bf16(b.z, b.w);
    return r.v;
}

// ---------------------------------------------------------------------------
// x (fp32 [256][512]) -> x_bf (bf16 packed dwords)
// ---------------------------------------------------------------------------
__global__ __launch_bounds__(256) void xbf_kernel(
    const float* __restrict__ x, unsigned* __restrict__ xb)
{
    int i = blockIdx.x * 256 + threadIdx.x;
    float2 v = *(const float2*)&x[(size_t)i * 2];
    xb[i] = pk_bf16(v.x, v.y);
}

// ---------------------------------------------------------------------------
// xproj via MFMA, software-pipelined, fused h1 = tanh(xp) epilogue.
// grid 864 (16-n tiles), 4 waves; wave w covers b = w*64..w*64+63 (4 tiles).
// ---------------------------------------------------------------------------
__global__ __launch_bounds__(256) void xproj_mfma(
    const float* __restrict__ w_in, const float* __restrict__ bias,
    const short* __restrict__ xbf, unsigned short* __restrict__ xp,
    unsigned short* __restrict__ h1)
{
    const int tid = threadIdx.x, w = tid >> 6, lane = tid & 63;
    const int quad = lane >> 4, l16 = lane & 15;
    const int n0 = blockIdx.x * 16;
    const float* __restrict__ arow = &w_in[(size_t)(n0 + l16) * KDIM];

    f32x4 acc[4] = {};

    int ka = quad * 8;
    float4 a0 = *(const float4*)&arow[ka];
    float4 a1 = *(const float4*)&arow[ka + 4];
    bf8 bb[4];
#pragma unroll
    for (int j = 0; j < 4; ++j)
        bb[j] = *(const bf8*)&xbf[(size_t)(w * 64 + j * 16 + l16) * KDIM + ka];

    for (int it = 0; it < 16; ++it) {
        float4 na0{}, na1{}; bf8 nb[4] = {};
        if (it < 15) {
            const int nka = ka + 32;
            na0 = *(const float4*)&arow[nka];
            na1 = *(const float4*)&arow[nka + 4];
#pragma unroll
            for (int j = 0; j < 4; ++j)
                nb[j] = *(const bf8*)&xbf[(size_t)(w * 64 + j * 16 + l16) * KDIM + nka];
        }
        bf8 af = cvt8(a0, a1);
#pragma unroll
        for (int j = 0; j < 4; ++j)
            acc[j] = __builtin_amdgcn_mfma_f32_16x16x32_bf16(af, bb[j], acc[j], 0, 0, 0);
        a0 = na0; a1 = na1;
#pragma unroll
        for (int j = 0; j < 4; ++j) bb[j] = nb[j];
        ka += 32;
    }

#pragma unroll
    for (int j = 0; j < 4; ++j) {
        const int b = w * 64 + j * 16 + l16;
#pragma unroll
        for (int r = 0; r < 4; ++r) {
            const int n = n0 + quad * 4 + r;
            const float v = acc[j][r] + bias[n];
            xp[(size_t)n * BB + b] = bf_rne(v);
            h1[(size_t)n * BB + b] = bf_rne(fast_tanh(v));
        }
    }
}

// ---------------------------------------------------------------------------
// Recurrent step v5: packed in-flight planes (dwords), unpack-once on
// promotion to the active float2 ring. x-chunk 8 -> grid 1728 (6.75 blk/CU,
// single residency round). xp prefetched for all 8 xi in the prologue.
// __launch_bounds__(128,4) pins 4 waves/SIMD (VGPR <= 128).
// bid&7 == z/3 (XCD slab), 1728 = 8*216.
// ---------------------------------------------------------------------------
__device__ __forceinline__ void load_plane_pk(
    const unsigned* __restrict__ h32, int z, int y, int xx, int dof,
    unsigned* pk)
{
#pragma unroll
    for (int j = 0; j < 9; ++j) {
        const int dz = j / 3 - 1, dy = j % 3 - 1;
        const int zz = z + dz, yy = y + dy;
        const bool valid = (xx >= 0) & (xx < CUBE) & (zz >= 0) & (zz < CUBE) &
                           (yy >= 0) & (yy < CUBE);   // wave-uniform
        unsigned v = 0u;
        if (valid) v = h32[(size_t)((zz * 24 + yy) * 24 + xx) * 128 + dof];
        pk[j] = v;
    }
}
__device__ __forceinline__ void unpack9(const unsigned* pk, float2* u) {
#pragma unroll
    for (int j = 0; j < 9; ++j)
        u[j] = make_float2(bf_lo(pk[j]), bf_hi(pk[j]));
}

__global__ __launch_bounds__(128, 4) void step_kernel(
    const unsigned* __restrict__ hprev, const unsigned* __restrict__ xp,
    const float* __restrict__ wl, unsigned* __restrict__ hnext)
{
    const int tid  = threadIdx.x;
    const int wv   = __builtin_amdgcn_readfirstlane(tid >> 6);  // batch half
    const int lane = tid & 63;

    const int bid   = blockIdx.x;
    const int zhi   = bid & 7;
    const int inner = bid >> 3;       // 0..215
    const int y     = inner % 24;
    const int r     = inner / 24;     // 0..8
    const int xc    = r % 3;
    const int zlo   = r / 3;
    const int z     = zhi * 3 + zlo;

    const int x0  = xc * 8;
    const int dof = wv * 64 + lane;   // dword offset (2 batch elems)
    const int n0  = (z * 24 + y) * 24 + x0;

    unsigned pk[2][9];                // in-flight planes (packed, dist-2)
    unsigned tm[9], tc[9];
    float2   u[3][9];                 // active planes x-1, x, x+1 (ring)

    load_plane_pk(hprev, z, y, x0 - 1, dof, tm);
    load_plane_pk(hprev, z, y, x0,     dof, tc);
    load_plane_pk(hprev, z, y, x0 + 1, dof, pk[0]);
    load_plane_pk(hprev, z, y, x0 + 2, dof, pk[1]);

    unsigned xpv[8];
#pragma unroll
    for (int xi = 0; xi < 8; ++xi)
        xpv[xi] = xp[(size_t)(n0 + xi) * 128 + dof];

    unpack9(tm, u[0]);
    unpack9(tc, u[1]);

#pragma unroll
    for (int xi = 0; xi < 8; ++xi) {
        // promote plane x0+xi+1 (loaded 2 iters ago) into the active ring
        unpack9(pk[xi & 1], u[(xi + 2) % 3]);
        // prefetch plane x0+xi+3 into the freed packed slot
        if (xi <= 5)
            load_plane_pk(hprev, z, y, x0 + xi + 3, dof, pk[xi & 1]);

        const int n = n0 + xi;                        // wave-uniform
        const float* __restrict__ wn = &wl[(size_t)n * 27];
        const float2* pm = u[xi % 3];
        const float2* pc = u[(xi + 1) % 3];
        const float2* pp = u[(xi + 2) % 3];

        float2 a0 = make_float2(bf_lo(xpv[xi]), bf_hi(xpv[xi]));
        float2 a1 = make_float2(0.f, 0.f);
        float2 a2 = make_float2(0.f, 0.f);
#pragma unroll
        for (int j = 0; j < 9; ++j) {
            const float w0 = wn[3 * j + 0];
            const float w1 = wn[3 * j + 1];
            const float w2 = wn[3 * j + 2];
            a0.x += w0 * pm[j].x; a0.y += w0 * pm[j].y;
            a1.x += w1 * pc[j].x; a1.y += w1 * pc[j].y;
            a2.x += w2 * pp[j].x; a2.y += w2 * pp[j].y;
        }
        const float sx = a0.x + a1.x + a2.x;
        const float sy = a0.y + a1.y + a2.y;
        hnext[(size_t)n * 128 + dof] = pk_bf16(fast_tanh(sx), fast_tanh(sy));
    }
}

// ---------------------------------------------------------------------------
// Transpose h[k][b] -> hT[b][k] (bf16), 64x64 tiles via LDS.
// ---------------------------------------------------------------------------
__global__ __launch_bounds__(256) void transpose_kernel(
    const unsigned* __restrict__ h32, unsigned* __restrict__ hT32)
{
    __shared__ unsigned short T[64][66];
    const int tid = threadIdx.x;
    const int rr = tid >> 2, g = tid & 3;
    const int k0 = blockIdx.x * 64, b0 = blockIdx.y * 64;
#pragma unroll
    for (int i = 0; i < 8; ++i) {
        unsigned d = h32[(size_t)(k0 + rr) * 128 + b0 / 2 + g * 8 + i];
        const int bl = (g * 8 + i) * 2;
        T[bl][rr]     = (unsigned short)(d & 0xffffu);
        T[bl + 1][rr] = (unsigned short)(d >> 16);
    }
    __syncthreads();
#pragma unroll
    for (int i = 0; i < 8; ++i) {
        const int kl = (g * 8 + i) * 2;
        unsigned d = (unsigned)T[rr][kl] | ((unsigned)T[rr][kl + 1] << 16);
        hT32[(size_t)(b0 + rr) * (NN / 2) + k0 / 2 + g * 8 + i] = d;
    }
}

// ---------------------------------------------------------------------------
// Output GEMM via MFMA, split-K=16, o-tile 16 -> grid (63,16)=1008 blocks
// (~4 blk/CU, 2x occupancy vs o-tile-32), prefetch depth 2 with a fully
// unrolled static 2-stage ring (no runtime-indexed vector arrays).
// Block = 4 waves; wave w covers 16o x 64b. W_out read once (fp32->bf16 cvt).
// ---------------------------------------------------------------------------
__global__ __launch_bounds__(256) void outgemm_mfma(
    const float* __restrict__ wout, const short* __restrict__ hT,
    float* __restrict__ part)
{
    const int tid = threadIdx.x, w = tid >> 6, lane = tid & 63;
    const int quad = lane >> 4, l16 = lane & 15;
    const int o0 = blockIdx.x * 16;
    const int kb = blockIdx.y * (NN / KS);   // 864-wide K chunk, 27 iters of 32
    const int b0 = w * 64;

    const int oa = o0 + l16;
    const bool av = oa < ODIM;
    const float* __restrict__ ar = &wout[(size_t)oa * NN];
    const float4 z4 = {0.f, 0.f, 0.f, 0.f};

    f32x4 acc[4] = {};

    float4 A0[2], A1[2];
    bf8    Bv[2][4];

#pragma unroll
    for (int s = 0; s < 2; ++s) {
        const int ka = kb + s * 32 + quad * 8;
        A0[s] = av ? *(const float4*)&ar[ka]     : z4;
        A1[s] = av ? *(const float4*)&ar[ka + 4] : z4;
#pragma unroll
        for (int j = 0; j < 4; ++j)
            Bv[s][j] = *(const bf8*)&hT[(size_t)(b0 + j * 16 + l16) * NN + ka];
    }

#pragma unroll
    for (int it = 0; it < 27; ++it) {
        const int s = it & 1;                 // compile-time under full unroll
        bf8 af = cvt8(A0[s], A1[s]);
#pragma unroll
        for (int j = 0; j < 4; ++j)
            acc[j] = __builtin_amdgcn_mfma_f32_16x16x32_bf16(af, Bv[s][j], acc[j], 0, 0, 0);
        if (it + 2 < 27) {                    // refill stage s for iter it+2
            const int ka = kb + (it + 2) * 32 + quad * 8;
            A0[s] = av ? *(const float4*)&ar[ka]     : z4;
            A1[s] = av ? *(const float4*)&ar[ka + 4] : z4;
#pragma unroll
            for (int j = 0; j < 4; ++j)
                Bv[s][j] = *(const bf8*)&hT[(size_t)(b0 + j * 16 + l16) * NN + ka];
        }
    }

#pragma unroll
    for (int j = 0; j < 4; ++j) {
        const int b = b0 + j * 16 + l16;
#pragma unroll
        for (int r = 0; r < 4; ++r) {
            const int o = o0 + quad * 4 + r;
            part[((size_t)blockIdx.y * 1024 + o) * BB + b] = acc[j][r];
        }
    }
}

// out[b*1000+o] = bias[o] + sum_kc part[kc][o][b]; block per o, lanes = b.
__global__ __launch_bounds__(256) void reduce_kernel(
    const float* __restrict__ part, const float* __restrict__ bias,
    float* __restrict__ out)
{
    const int o = blockIdx.x, b = threadIdx.x;
    float s = bias[o];
#pragma unroll
    for (int kc = 0; kc < KS; ++kc)
        s += part[((size_t)kc * 1024 + o) * BB + b];
    out[(size_t)b * ODIM + o] = s;
}

extern "C" void kernel_launch(void* const* d_in, const int* in_sizes, int n_in,
                              void* d_out, int out_size, void* d_ws, size_t ws_size,
                              hipStream_t stream)
{
    const float* x       = (const float*)d_in[0];
    const float* w_in    = (const float*)d_in[1];
    const float* b_in    = (const float*)d_in[2];
    const float* w_local = (const float*)d_in[3];
    const float* w_out   = (const float*)d_in[4];
    const float* b_out   = (const float*)d_in[5];
    float* out = (float*)d_out;

    char* p = (char*)d_ws;
    unsigned short* xp_bf = (unsigned short*)p;          p += (size_t)NN * BB * 2;
    unsigned short* hA    = (unsigned short*)p;          p += (size_t)NN * BB * 2;
    unsigned short* hB    = (unsigned short*)p;          p += (size_t)NN * BB * 2;
    unsigned short* hT    = (unsigned short*)p;          p += (size_t)NN * BB * 2;
    unsigned short* x_bf  = (unsigned short*)p;          p += (size_t)BB * KDIM * 2;
    float*          part  = (float*)p;                   // KS*1024*BB floats

    xbf_kernel<<<256, 256, 0, stream>>>(x, (unsigned*)x_bf);
    xproj_mfma<<<864, 256, 0, stream>>>(w_in, b_in, (const short*)x_bf, xp_bf, hA);

    const unsigned* hp = (const unsigned*)hA;
    unsigned* hn = (unsigned*)hB;
    for (int s = 0; s < 29; ++s) {          // 29 odd -> final state in hB
        step_kernel<<<1728, 128, 0, stream>>>(hp, (const unsigned*)xp_bf, w_local, hn);
        unsigned* t = (unsigned*)hp; hp = hn; hn = t;
    }

    transpose_kernel<<<dim3(216, 4), 256, 0, stream>>>(hp, (unsigned*)hT);
    outgemm_mfma<<<dim3(63, KS), 256, 0, stream>>>(w_out, (const short*)hT, part);
    reduce_kernel<<<ODIM, 256, 0, stream>>>(part, b_out, out);
}

// Round 2
// 559.223 us; speedup vs baseline: 1.2249x; 1.2249x over previous
//
#include <hip/hip_runtime.h>
#include <hip/hip_bf16.h>

#define NN   13824     // 24^3 neurons
#define BB   256       // batch
#define KDIM 512       // input dim
#define ODIM 1000      // output dim
#define CUBE 24
#define KS   16        // out-gemm split-K

typedef short bf8 __attribute__((ext_vector_type(8)));     // 8 bf16 (4 VGPRs)
typedef float f32x4 __attribute__((ext_vector_type(4)));   // MFMA acc

__device__ __forceinline__ float fast_tanh(float a) {
    float e = __expf(2.0f * a);
    return 1.0f - 2.0f / (e + 1.0f);
}
__device__ __forceinline__ float bf_lo(unsigned u) { return __uint_as_float(u << 16); }
__device__ __forceinline__ float bf_hi(unsigned u) { return __uint_as_float(u & 0xffff0000u); }
__device__ __forceinline__ unsigned short bf_rne(float f) {
    unsigned u = __float_as_uint(f);
    u += 0x7fffu + ((u >> 16) & 1u);
    return (unsigned short)(u >> 16);
}
// packed fp32x2 -> bf16x2 via v_cvt_pk_bf16_f32 (one inst on gfx950)
__device__ __forceinline__ unsigned pk_bf16(float lo, float hi) {
    union { __hip_bfloat162 h; unsigned u; } cv;
    cv.h = __float22bfloat162_rn(make_float2(lo, hi));
    return cv.u;
}
__device__ __forceinline__ bf8 cvt8(float4 a, float4 b) {
    union { bf8 v; unsigned u[4]; } r;
    r.u[0] = pk_bf16(a.x, a.y);
    r.u[1] = pk_bf16(a.z, a.w);
    r.u[2] = pk_bf16(b.x, b.y);
    r.u[3] = pk_bf16(b.z, b.w);
    return r.v;
}

// ---------------------------------------------------------------------------
// x (fp32 [256][512]) -> x_bf (bf16 packed dwords)
// ---------------------------------------------------------------------------
__global__ __launch_bounds__(256) void xbf_kernel(
    const float* __restrict__ x, unsigned* __restrict__ xb)
{
    int i = blockIdx.x * 256 + threadIdx.x;
    float2 v = *(const float2*)&x[(size_t)i * 2];
    xb[i] = pk_bf16(v.x, v.y);
}

// ---------------------------------------------------------------------------
// xproj via MFMA, software-pipelined, fused h1 = tanh(xp) epilogue.
// grid 864 (16-n tiles), 4 waves; wave w covers b = w*64..w*64+63 (4 tiles).
// ---------------------------------------------------------------------------
__global__ __launch_bounds__(256) void xproj_mfma(
    const float* __restrict__ w_in, const float* __restrict__ bias,
    const short* __restrict__ xbf, unsigned short* __restrict__ xp,
    unsigned short* __restrict__ h1)
{
    const int tid = threadIdx.x, w = tid >> 6, lane = tid & 63;
    const int quad = lane >> 4, l16 = lane & 15;
    const int n0 = blockIdx.x * 16;
    const float* __restrict__ arow = &w_in[(size_t)(n0 + l16) * KDIM];

    f32x4 acc[4] = {};

    int ka = quad * 8;
    float4 a0 = *(const float4*)&arow[ka];
    float4 a1 = *(const float4*)&arow[ka + 4];
    bf8 bb[4];
#pragma unroll
    for (int j = 0; j < 4; ++j)
        bb[j] = *(const bf8*)&xbf[(size_t)(w * 64 + j * 16 + l16) * KDIM + ka];

    for (int it = 0; it < 16; ++it) {
        float4 na0{}, na1{}; bf8 nb[4] = {};
        if (it < 15) {
            const int nka = ka + 32;
            na0 = *(const float4*)&arow[nka];
            na1 = *(const float4*)&arow[nka + 4];
#pragma unroll
            for (int j = 0; j < 4; ++j)
                nb[j] = *(const bf8*)&xbf[(size_t)(w * 64 + j * 16 + l16) * KDIM + nka];
        }
        bf8 af = cvt8(a0, a1);
#pragma unroll
        for (int j = 0; j < 4; ++j)
            acc[j] = __builtin_amdgcn_mfma_f32_16x16x32_bf16(af, bb[j], acc[j], 0, 0, 0);
        a0 = na0; a1 = na1;
#pragma unroll
        for (int j = 0; j < 4; ++j) bb[j] = nb[j];
        ka += 32;
    }

#pragma unroll
    for (int j = 0; j < 4; ++j) {
        const int b = w * 64 + j * 16 + l16;
#pragma unroll
        for (int r = 0; r < 4; ++r) {
            const int n = n0 + quad * 4 + r;
            const float v = acc[j][r] + bias[n];
            xp[(size_t)n * BB + b] = bf_rne(v);
            h1[(size_t)n * BB + b] = bf_rne(fast_tanh(v));
        }
    }
}

// ---------------------------------------------------------------------------
// Recurrent step v6: v4 inner loop (float2 ring-5, x-chunk 6) with 4-wave
// blocks pairing two adjacent y-lines (L1 sharing of overlapping neighbor
// rows; 18->12 rows/plane per block = 1.33x less L2 traffic) at UNCHANGED
// occupancy (1152 blocks x 4 waves = 18 waves/CU, same as v4's 2304x2).
// bid&7 == z/3 keeps the z-slab -> XCD L2 pinning.
// ---------------------------------------------------------------------------
__device__ __forceinline__ void load_plane_f2(
    const unsigned* __restrict__ h32, int z, int y, int xx, int dof, float2* w9)
{
#pragma unroll
    for (int j = 0; j < 9; ++j) {
        const int dz = j / 3 - 1, dy = j % 3 - 1;
        const int zz = z + dz, yy = y + dy;
        const bool valid = (xx >= 0) & (xx < CUBE) & (zz >= 0) & (zz < CUBE) &
                           (yy >= 0) & (yy < CUBE);   // wave-uniform
        unsigned v = 0u;
        if (valid) v = h32[(size_t)((zz * 24 + yy) * 24 + xx) * 128 + dof];
        w9[j] = make_float2(bf_lo(v), bf_hi(v));
    }
}

__global__ __launch_bounds__(256) void step_kernel(
    const unsigned* __restrict__ hprev, const unsigned* __restrict__ xp,
    const float* __restrict__ wl, unsigned* __restrict__ hnext)
{
    const int tid  = threadIdx.x;
    const int wid  = __builtin_amdgcn_readfirstlane(tid >> 6);  // 0..3
    const int wvb  = wid & 1;          // batch half
    const int yoff = wid >> 1;         // y within the pair
    const int lane = tid & 63;

    const int bid   = blockIdx.x;
    const int zhi   = bid & 7;
    const int inner = bid >> 3;       // 0..143
    const int yp    = inner % 12;
    const int r     = inner / 12;     // 0..11
    const int xc    = r & 3;
    const int zlo   = r >> 2;
    const int z     = zhi * 3 + zlo;
    const int y     = yp * 2 + yoff;

    const int x0   = xc * 6;
    const int dof  = wvb * 64 + lane;  // dword offset (2 batch elems)

    float2 win[5][9];
    load_plane_f2(hprev, z, y, x0 - 1, dof, win[0]);
    load_plane_f2(hprev, z, y, x0,     dof, win[1]);
    load_plane_f2(hprev, z, y, x0 + 1, dof, win[2]);
    load_plane_f2(hprev, z, y, x0 + 2, dof, win[3]);

#pragma unroll
    for (int xi = 0; xi < 6; ++xi) {
        const int x = x0 + xi;
        if (xi <= 3)
            load_plane_f2(hprev, z, y, x + 3, dof, win[(xi + 4) % 5]);

        const int n = (z * 24 + y) * 24 + x;          // wave-uniform
        const float* __restrict__ wn = &wl[(size_t)n * 27];
        const unsigned xpv = xp[(size_t)n * 128 + dof];
        float2 acc = make_float2(bf_lo(xpv), bf_hi(xpv));

        const float2* pm = win[xi % 5];
        const float2* pc = win[(xi + 1) % 5];
        const float2* pp = win[(xi + 2) % 5];
#pragma unroll
        for (int j = 0; j < 9; ++j) {
            const float w0 = wn[3 * j + 0];
            const float w1 = wn[3 * j + 1];
            const float w2 = wn[3 * j + 2];
            acc.x += w0 * pm[j].x + w1 * pc[j].x + w2 * pp[j].x;
            acc.y += w0 * pm[j].y + w1 * pc[j].y + w2 * pp[j].y;
        }
        hnext[(size_t)n * 128 + dof] = pk_bf16(fast_tanh(acc.x), fast_tanh(acc.y));
    }
}

// ---------------------------------------------------------------------------
// Transpose h[k][b] -> hT[b][k] (bf16), 64x64 tiles via LDS.
// ---------------------------------------------------------------------------
__global__ __launch_bounds__(256) void transpose_kernel(
    const unsigned* __restrict__ h32, unsigned* __restrict__ hT32)
{
    __shared__ unsigned short T[64][66];
    const int tid = threadIdx.x;
    const int rr = tid >> 2, g = tid & 3;
    const int k0 = blockIdx.x * 64, b0 = blockIdx.y * 64;
#pragma unroll
    for (int i = 0; i < 8; ++i) {
        unsigned d = h32[(size_t)(k0 + rr) * 128 + b0 / 2 + g * 8 + i];
        const int bl = (g * 8 + i) * 2;
        T[bl][rr]     = (unsigned short)(d & 0xffffu);
        T[bl + 1][rr] = (unsigned short)(d >> 16);
    }
    __syncthreads();
#pragma unroll
    for (int i = 0; i < 8; ++i) {
        const int kl = (g * 8 + i) * 2;
        unsigned d = (unsigned)T[rr][kl] | ((unsigned)T[rr][kl + 1] << 16);
        hT32[(size_t)(b0 + rr) * (NN / 2) + k0 / 2 + g * 8 + i] = d;
    }
}

// ---------------------------------------------------------------------------
// Output GEMM v3: L3-B-traffic fix. hT (7MB) does not fit a 4MB per-XCD L2,
// so every o-block re-reads it from L3 (~3.6 TB/s observed ceiling). Round-0
// wasted 226MB on this. New decomposition: block = o-tile 128 (4 waves x 32o)
// x 64b x 864K; ALL 4 waves read IDENTICAL B addresses -> L1-shared, so B
// traffic beyond L1 = 512 blocks x 110KB = 56MB (4x cut). W_out still read
// exactly once (55MB HBM). Per-wave inner loop = round-0's proven
// depth-1 dynamic-loop pipeline (do NOT fully unroll: the compiler collapses
// a static ring to save VGPRs and destroys the prefetch - round-1 lesson).
// Grid (8 o-blocks, 4 b-chunks, 16 K-chunks) = 512 blocks.
// ---------------------------------------------------------------------------
__global__ __launch_bounds__(256) void outgemm_mfma(
    const float* __restrict__ wout, const short* __restrict__ hT,
    float* __restrict__ part)
{
    const int tid = threadIdx.x, w = tid >> 6, lane = tid & 63;
    const int quad = lane >> 4, l16 = lane & 15;
    const int o0 = blockIdx.x * 128 + w * 32;
    const int kb = blockIdx.z * (NN / KS);   // 864-wide K chunk, 27 iters of 32
    const int b0 = blockIdx.y * 64;

    const int oa = o0 + l16, ob = o0 + 16 + l16;
    const bool av0 = oa < ODIM, av1 = ob < ODIM;
    const float* __restrict__ ar0 = &wout[(size_t)oa * NN];
    const float* __restrict__ ar1 = &wout[(size_t)ob * NN];
    const float4 z4 = {0.f, 0.f, 0.f, 0.f};

    f32x4 acc[2][4] = {};

    int ka = kb + quad * 8;
    float4 a00 = av0 ? *(const float4*)&ar0[ka]     : z4;
    float4 a01 = av0 ? *(const float4*)&ar0[ka + 4] : z4;
    float4 a10 = av1 ? *(const float4*)&ar1[ka]     : z4;
    float4 a11 = av1 ? *(const float4*)&ar1[ka + 4] : z4;
    bf8 bb[4];
#pragma unroll
    for (int j = 0; j < 4; ++j)
        bb[j] = *(const bf8*)&hT[(size_t)(b0 + j * 16 + l16) * NN + ka];

    for (int it = 0; it < 27; ++it) {
        float4 na00{}, na01{}, na10{}, na11{}; bf8 nb[4] = {};
        if (it < 26) {
            const int nka = ka + 32;
            na00 = av0 ? *(const float4*)&ar0[nka]     : z4;
            na01 = av0 ? *(const float4*)&ar0[nka + 4] : z4;
            na10 = av1 ? *(const float4*)&ar1[nka]     : z4;
            na11 = av1 ? *(const float4*)&ar1[nka + 4] : z4;
#pragma unroll
            for (int j = 0; j < 4; ++j)
                nb[j] = *(const bf8*)&hT[(size_t)(b0 + j * 16 + l16) * NN + nka];
        }
        bf8 af0 = cvt8(a00, a01);
        bf8 af1 = cvt8(a10, a11);
#pragma unroll
        for (int j = 0; j < 4; ++j) {
            acc[0][j] = __builtin_amdgcn_mfma_f32_16x16x32_bf16(af0, bb[j], acc[0][j], 0, 0, 0);
            acc[1][j] = __builtin_amdgcn_mfma_f32_16x16x32_bf16(af1, bb[j], acc[1][j], 0, 0, 0);
        }
        a00 = na00; a01 = na01; a10 = na10; a11 = na11;
#pragma unroll
        for (int j = 0; j < 4; ++j) bb[j] = nb[j];
        ka += 32;
    }

#pragma unroll
    for (int i = 0; i < 2; ++i)
#pragma unroll
        for (int j = 0; j < 4; ++j) {
            const int b = b0 + j * 16 + l16;
#pragma unroll
            for (int r = 0; r < 4; ++r) {
                const int o = o0 + i * 16 + quad * 4 + r;
                if (o < 1024)
                    part[((size_t)blockIdx.z * 1024 + o) * BB + b] = acc[i][j][r];
            }
        }
}

// out[b*1000+o] = bias[o] + sum_kc part[kc][o][b]; block per o, lanes = b.
__global__ __launch_bounds__(256) void reduce_kernel(
    const float* __restrict__ part, const float* __restrict__ bias,
    float* __restrict__ out)
{
    const int o = blockIdx.x, b = threadIdx.x;
    float s = bias[o];
#pragma unroll
    for (int kc = 0; kc < KS; ++kc)
        s += part[((size_t)kc * 1024 + o) * BB + b];
    out[(size_t)b * ODIM + o] = s;
}

extern "C" void kernel_launch(void* const* d_in, const int* in_sizes, int n_in,
                              void* d_out, int out_size, void* d_ws, size_t ws_size,
                              hipStream_t stream)
{
    const float* x       = (const float*)d_in[0];
    const float* w_in    = (const float*)d_in[1];
    const float* b_in    = (const float*)d_in[2];
    const float* w_local = (const float*)d_in[3];
    const float* w_out   = (const float*)d_in[4];
    const float* b_out   = (const float*)d_in[5];
    float* out = (float*)d_out;

    char* p = (char*)d_ws;
    unsigned short* xp_bf = (unsigned short*)p;          p += (size_t)NN * BB * 2;
    unsigned short* hA    = (unsigned short*)p;          p += (size_t)NN * BB * 2;
    unsigned short* hB    = (unsigned short*)p;          p += (size_t)NN * BB * 2;
    unsigned short* hT    = (unsigned short*)p;          p += (size_t)NN * BB * 2;
    unsigned short* x_bf  = (unsigned short*)p;          p += (size_t)BB * KDIM * 2;
    float*          part  = (float*)p;                   // KS*1024*BB floats

    xbf_kernel<<<256, 256, 0, stream>>>(x, (unsigned*)x_bf);
    xproj_mfma<<<864, 256, 0, stream>>>(w_in, b_in, (const short*)x_bf, xp_bf, hA);

    const unsigned* hp = (const unsigned*)hA;
    unsigned* hn = (unsigned*)hB;
    for (int s = 0; s < 29; ++s) {          // 29 odd -> final state in hB
        step_kernel<<<1152, 256, 0, stream>>>(hp, (const unsigned*)xp_bf, w_local, hn);
        unsigned* t = (unsigned*)hp; hp = hn; hn = t;
    }

    transpose_kernel<<<dim3(216, 4), 256, 0, stream>>>(hp, (unsigned*)hT);
    outgemm_mfma<<<dim3(8, 4, KS), 256, 0, stream>>>(w_out, (const short*)hT, part);
    reduce_kernel<<<ODIM, 256, 0, stream>>>(part, b_out, out);
}